// Round 1
// baseline (2057.145 us; speedup 1.0000x reference)
//
#include <hip/hip_runtime.h>
#include <stdint.h>

#define N_NODES 1000000
#define HID 256
#define HH  128
#define NG  1024

typedef short short8v __attribute__((ext_vector_type(8)));
typedef float f32x4 __attribute__((ext_vector_type(4)));

// f32 -> bf16 (RNE), inputs finite
__device__ __forceinline__ unsigned short f2bf(float f){
  unsigned u = __float_as_uint(f);
  u += 0x7FFFu + ((u >> 16) & 1u);
  return (unsigned short)(u >> 16);
}

// monotonic float <-> uint key (for atomicMax over signed floats)
__device__ __forceinline__ unsigned fkey(float f){
  unsigned u = __float_as_uint(f);
  return (u & 0x80000000u) ? ~u : (u | 0x80000000u);
}
__device__ __forceinline__ float funkey(unsigned k){
  unsigned u = (k & 0x80000000u) ? (k & 0x7FFFFFFFu) : ~k;
  return __uint_as_float(u);
}

__device__ __forceinline__ float fast_tanh(float v){
  float e = __expf(2.f * v);
  return 1.f - 2.f / (e + 1.f);
}

// --- transform w1 [256][128] f32 -> bf16 B-fragment layout in ws ---
// layout: [nt(8)][ks(8)][lane(64)][i(8)]  where B[k][n]: n = nt*16 + (lane&15),
// k = ks*32 + (lane>>4)*8 + i
__global__ void k_prep(const float* __restrict__ w1, unsigned short* __restrict__ w1f){
  int s = blockIdx.x * blockDim.x + threadIdx.x;
  if (s >= 4096) return;
  int nt = s >> 9, rem = s & 511, ks = rem >> 6, lane = rem & 63;
  int q = lane >> 4, c = lane & 15;
  union { unsigned short u[8]; uint4 v; } tmp;
  for (int i = 0; i < 8; ++i){
    int k = ks * 32 + q * 8 + i;
    int n = nt * 16 + c;
    tmp.u[i] = f2bf(w1[k * HH + n]);
  }
  *(uint4*)(w1f + (size_t)s * 8) = tmp.v;
}

// --- scores: per wave 16 nodes, MFMA 16x16x32 bf16, K=256, N=128 ---
__global__ __launch_bounds__(256) void k_score(
    const float* __restrict__ x, const unsigned short* __restrict__ w1f,
    const float* __restrict__ b1, const float* __restrict__ w2,
    const float* __restrict__ b2, float* __restrict__ scores, int num_tiles)
{
  __shared__ unsigned short w1s[32768]; // 64 KB, [nt][ks][lane][8]
  const int tid = threadIdx.x;
  for (int i = tid; i < 4096; i += 256)
    ((uint4*)w1s)[i] = ((const uint4*)w1f)[i];
  __syncthreads();

  const int wave = tid >> 6, lane = tid & 63;
  const int q = lane >> 4, col = lane & 15;

  float b1v[8], w2v[8];
  #pragma unroll
  for (int nt = 0; nt < 8; ++nt){
    int j = nt * 16 + col;
    b1v[nt] = b1[j];
    w2v[nt] = w2[j];
  }
  const float b2v = b2[0];

  for (int tile = blockIdx.x; tile < num_tiles; tile += gridDim.x){
    const int node0 = tile * 64 + wave * 16;
    f32x4 acc[8];
    #pragma unroll
    for (int nt = 0; nt < 8; ++nt) acc[nt] = (f32x4){0.f, 0.f, 0.f, 0.f};

    const float* xrow = x + (size_t)(node0 + col) * HID;
    #pragma unroll
    for (int ks = 0; ks < 8; ++ks){
      const float4* xp = (const float4*)(xrow + ks * 32 + q * 8);
      float4 xa = xp[0], xb = xp[1];
      short8v a;
      a[0] = (short)f2bf(xa.x); a[1] = (short)f2bf(xa.y);
      a[2] = (short)f2bf(xa.z); a[3] = (short)f2bf(xa.w);
      a[4] = (short)f2bf(xb.x); a[5] = (short)f2bf(xb.y);
      a[6] = (short)f2bf(xb.z); a[7] = (short)f2bf(xb.w);
      #pragma unroll
      for (int nt = 0; nt < 8; ++nt){
        short8v bfr = *(const short8v*)&w1s[(((size_t)nt * 8 + ks) * 64 + lane) * 8];
        acc[nt] = __builtin_amdgcn_mfma_f32_16x16x32_bf16(a, bfr, acc[nt], 0, 0, 0);
      }
    }
    // epilogue: score[m] = sum_j tanh(h + b1[j]) * w2[j] + b2
    // C layout: col = lane&15 (j within nt), row m = q*4 + r
    #pragma unroll
    for (int r = 0; r < 4; ++r){
      float p = 0.f;
      #pragma unroll
      for (int nt = 0; nt < 8; ++nt)
        p += fast_tanh(acc[nt][r] + b1v[nt]) * w2v[nt];
      p += __shfl_xor(p, 1);
      p += __shfl_xor(p, 2);
      p += __shfl_xor(p, 4);
      p += __shfl_xor(p, 8);
      if (col == r)
        scores[node0 + q * 4 + r] = p + b2v;
    }
  }
}

// --- segment max via atomicMax on monotonic keys, 16 nodes/thread ---
__global__ void k_segmax(const float* __restrict__ scores, const int* __restrict__ batch,
                         unsigned* __restrict__ segkey){
  long t = (long)blockIdx.x * blockDim.x + threadIdx.x;
  long n0 = t * 16;
  if (n0 >= N_NODES) return;
  long n1 = n0 + 16; if (n1 > N_NODES) n1 = N_NODES;
  int cur = -1; float mx = 0.f;
  for (long n = n0; n < n1; ++n){
    int b = batch[n];
    float s = scores[n];
    if (b != cur){
      if (cur >= 0) atomicMax(&segkey[cur], fkey(mx));
      cur = b; mx = s;
    } else {
      mx = fmaxf(mx, s);
    }
  }
  atomicMax(&segkey[cur], fkey(mx));
}

// --- segment sum of exp(score - max) ---
__global__ void k_denom(const float* __restrict__ scores, const int* __restrict__ batch,
                        const unsigned* __restrict__ segkey, float* __restrict__ denom){
  long t = (long)blockIdx.x * blockDim.x + threadIdx.x;
  long n0 = t * 16;
  if (n0 >= N_NODES) return;
  long n1 = n0 + 16; if (n1 > N_NODES) n1 = N_NODES;
  int cur = -1; float mb = 0.f, acc = 0.f;
  for (long n = n0; n < n1; ++n){
    int b = batch[n];
    if (b != cur){
      if (cur >= 0) atomicAdd(&denom[cur], acc);
      cur = b; mb = funkey(segkey[b]); acc = 0.f;
    }
    acc += expf(scores[n] - mb);
  }
  atomicAdd(&denom[cur], acc);
}

// --- attn[n] = exp(score - max)/denom ---
__global__ void k_attn(const float* __restrict__ scores, const int* __restrict__ batch,
                       const unsigned* __restrict__ segkey, const float* __restrict__ denom,
                       float* __restrict__ attn){
  long n = (long)blockIdx.x * blockDim.x + threadIdx.x;
  if (n >= N_NODES) return;
  int b = batch[n];
  attn[n] = expf(scores[n] - funkey(segkey[b])) / denom[b];
}

// --- pooling: thread owns one column; register-accumulate per graph run ---
__global__ __launch_bounds__(256) void k_pool(
    const float* __restrict__ x, const int* __restrict__ batch,
    const float* __restrict__ attn, float* __restrict__ out)
{
  __shared__ float a_s[1024];
  __shared__ int b_s[1024];
  const int tid = threadIdx.x;
  const long base = (long)blockIdx.x * 1024;
  int cnt = (int)(N_NODES - base); if (cnt > 1024) cnt = 1024;
  for (int i = tid; i < cnt; i += 256){
    a_s[i] = attn[base + i];
    b_s[i] = batch[base + i];
  }
  __syncthreads();

  float acc = 0.f;
  int cur = b_s[0];
  const float* xp = x + base * HID + tid;
  #pragma unroll 4
  for (int i = 0; i < cnt; ++i){
    int b = b_s[i];
    if (b != cur){
      atomicAdd(&out[(long)cur * HID + tid], acc);
      acc = 0.f; cur = b;
    }
    acc += a_s[i] * xp[(long)i * HID];
  }
  atomicAdd(&out[(long)cur * HID + tid], acc);
}

extern "C" void kernel_launch(void* const* d_in, const int* in_sizes, int n_in,
                              void* d_out, int out_size, void* d_ws, size_t ws_size,
                              hipStream_t stream){
  const float* x     = (const float*)d_in[0];
  const int*   batch = (const int*)d_in[1];
  const float* w1    = (const float*)d_in[2];
  const float* b1    = (const float*)d_in[3];
  const float* w2    = (const float*)d_in[4];
  const float* b2    = (const float*)d_in[5];
  float* out = (float*)d_out;

  char* ws = (char*)d_ws;
  unsigned short* w1f = (unsigned short*)ws;            // 65536 B
  float* scores = (float*)(ws + 65536);                 // 4,000,000 B
  float* attn   = (float*)(ws + 65536 + 4000000);       // 4,000,000 B
  unsigned* segkey = (unsigned*)(ws + 65536 + 8000000); // 4096 B
  float* denom  = (float*)(ws + 65536 + 8000000 + 4096);// 4096 B

  hipMemsetAsync(segkey, 0, 8192, stream);              // segkey(=key of -inf) + denom(=0)
  hipMemsetAsync(d_out, 0, (size_t)out_size * sizeof(float), stream);

  k_prep<<<16, 256, 0, stream>>>(w1, w1f);
  k_score<<<2048, 256, 0, stream>>>(x, w1f, b1, w2, b2, scores, N_NODES / 64);
  k_segmax<<<(62500 + 255) / 256, 256, 0, stream>>>(scores, batch, segkey);
  k_denom<<<(62500 + 255) / 256, 256, 0, stream>>>(scores, batch, segkey, denom);
  k_attn<<<(N_NODES + 255) / 256, 256, 0, stream>>>(scores, batch, segkey, denom, attn);
  k_pool<<<(N_NODES + 1023) / 1024, 256, 0, stream>>>(x, batch, attn, out);
}

// Round 2
// 1786.084 us; speedup vs baseline: 1.1518x; 1.1518x over previous
//
#include <hip/hip_runtime.h>
#include <stdint.h>

#define N_NODES 1000000
#define HID 256
#define HH  128
#define NG  1024

typedef short short8v __attribute__((ext_vector_type(8)));
typedef float f32x4 __attribute__((ext_vector_type(4)));

// f32 -> bf16 (RNE), inputs finite
__device__ __forceinline__ unsigned short f2bf(float f){
  unsigned u = __float_as_uint(f);
  u += 0x7FFFu + ((u >> 16) & 1u);
  return (unsigned short)(u >> 16);
}

__device__ __forceinline__ float fast_tanh(float v){
  float e = __expf(2.f * v);
  return 1.f - 2.f / (e + 1.f);
}

// --- transform w1 [256][128] f32 -> bf16 B-fragment layout in ws ---
// layout: [nt(8)][ks(8)][lane(64)][i(8)]  where B[k][n]: n = nt*16 + (lane&15),
// k = ks*32 + (lane>>4)*8 + i
__global__ void k_prep(const float* __restrict__ w1, unsigned short* __restrict__ w1f){
  int s = blockIdx.x * blockDim.x + threadIdx.x;
  if (s >= 4096) return;
  int nt = s >> 9, rem = s & 511, ks = rem >> 6, lane = rem & 63;
  int q = lane >> 4, c = lane & 15;
  union { unsigned short u[8]; uint4 v; } tmp;
  for (int i = 0; i < 8; ++i){
    int k = ks * 32 + q * 8 + i;
    int n = nt * 16 + c;
    tmp.u[i] = f2bf(w1[k * HH + n]);
  }
  *(uint4*)(w1f + (size_t)s * 8) = tmp.v;
}

// --- scores pass: per wave 16 nodes, MFMA 16x16x32 bf16, K=256, N=128.
// Writes e = exp(score) per node and atomically accumulates denom[graph].
// No max-subtraction: scores bounded (|s| <= sum|w2|+|b2| ~ 6), exp safe in f32,
// attention ratios mathematically identical to the max-subtracted reference.
__global__ __launch_bounds__(256) void k_score(
    const float* __restrict__ x, const unsigned short* __restrict__ w1f,
    const float* __restrict__ b1, const float* __restrict__ w2,
    const float* __restrict__ b2, const int* __restrict__ batch,
    float* __restrict__ escore, float* __restrict__ denom, int num_tiles)
{
  __shared__ unsigned short w1s[32768]; // 64 KB, [nt][ks][lane][8]
  const int tid = threadIdx.x;
  for (int i = tid; i < 4096; i += 256)
    ((uint4*)w1s)[i] = ((const uint4*)w1f)[i];
  __syncthreads();

  const int wave = tid >> 6, lane = tid & 63;
  const int q = lane >> 4, col = lane & 15;

  float b1v[8], w2v[8];
  #pragma unroll
  for (int nt = 0; nt < 8; ++nt){
    int j = nt * 16 + col;
    b1v[nt] = b1[j];
    w2v[nt] = w2[j];
  }
  const float b2v = b2[0];

  for (int tile = blockIdx.x; tile < num_tiles; tile += gridDim.x){
    const int node0 = tile * 64 + wave * 16;
    f32x4 acc[8];
    #pragma unroll
    for (int nt = 0; nt < 8; ++nt) acc[nt] = (f32x4){0.f, 0.f, 0.f, 0.f};

    const float* xrow = x + (size_t)(node0 + col) * HID;
    #pragma unroll
    for (int ks = 0; ks < 8; ++ks){
      const float4* xp = (const float4*)(xrow + ks * 32 + q * 8);
      float4 xa = xp[0], xb = xp[1];
      short8v a;
      a[0] = (short)f2bf(xa.x); a[1] = (short)f2bf(xa.y);
      a[2] = (short)f2bf(xa.z); a[3] = (short)f2bf(xa.w);
      a[4] = (short)f2bf(xb.x); a[5] = (short)f2bf(xb.y);
      a[6] = (short)f2bf(xb.z); a[7] = (short)f2bf(xb.w);
      #pragma unroll
      for (int nt = 0; nt < 8; ++nt){
        short8v bfr = *(const short8v*)&w1s[(((size_t)nt * 8 + ks) * 64 + lane) * 8];
        acc[nt] = __builtin_amdgcn_mfma_f32_16x16x32_bf16(a, bfr, acc[nt], 0, 0, 0);
      }
    }
    // epilogue: score[m] = sum_j tanh(h + b1[j]) * w2[j] + b2
    // C layout: col = lane&15 (j within nt), row m = q*4 + r
    float e_lane = 0.f;  // lane q*16+r (r<4) will hold e of node q*4+r
    #pragma unroll
    for (int r = 0; r < 4; ++r){
      float p = 0.f;
      #pragma unroll
      for (int nt = 0; nt < 8; ++nt)
        p += fast_tanh(acc[nt][r] + b1v[nt]) * w2v[nt];
      p += __shfl_xor(p, 1);
      p += __shfl_xor(p, 2);
      p += __shfl_xor(p, 4);
      p += __shfl_xor(p, 8);
      if (col == r){
        float e = __expf(p + b2v);
        e_lane = e;
        escore[node0 + q * 4 + r] = e;
      }
    }
    // denom accumulation: batch sorted -> usually all 16 nodes in one graph
    int bfirst = batch[node0];
    int blast  = batch[node0 + 15];
    if (bfirst == blast){
      float s = e_lane;
      s += __shfl_xor(s, 1);  s += __shfl_xor(s, 2);
      s += __shfl_xor(s, 16); s += __shfl_xor(s, 32);
      s += __shfl_xor(s, 4);  s += __shfl_xor(s, 8);
      if (lane == 0) atomicAdd(&denom[bfirst], s);
    } else if (col < 4){
      int b = batch[node0 + q * 4 + col];
      atomicAdd(&denom[b], e_lane);
    }
  }
}

// --- pooling: 4 node-groups x 64 lanes; lane owns 4 columns (float4).
// Per wave-instruction: 64 lanes x 16 B = 1 KB coalesced row read.
__global__ __launch_bounds__(256) void k_pool(
    const float* __restrict__ x, const int* __restrict__ batch,
    const float* __restrict__ escore, const float* __restrict__ denom,
    float* __restrict__ out)
{
  __shared__ float w_s[1024];
  __shared__ int b_s[1024];
  const int tid = threadIdx.x;
  const long base = (long)blockIdx.x * 1024;
  int cnt = (int)(N_NODES - base); if (cnt > 1024) cnt = 1024;
  for (int i = tid; i < cnt; i += 256){
    int b = batch[base + i];
    b_s[i] = b;
    w_s[i] = __fdividef(escore[base + i], denom[b]);
  }
  __syncthreads();

  const int g = tid >> 6;     // node-group: handles i = g, g+4, ...
  const int lane = tid & 63;  // owns columns [lane*4, lane*4+4)
  const float4* xp = (const float4*)(x + base * HID) + lane;

  float4 acc = {0.f, 0.f, 0.f, 0.f};
  int cur = b_s[g];
  float4 xv = {0.f, 0.f, 0.f, 0.f};
  if (g < cnt) xv = xp[(long)g * (HID / 4)];
  for (int i = g; i < cnt; i += 4){
    int inext = i + 4;
    float4 xnext = {0.f, 0.f, 0.f, 0.f};
    if (inext < cnt) xnext = xp[(long)inext * (HID / 4)];
    int b = b_s[i];
    float w = w_s[i];
    if (b != cur){
      float* o = &out[(long)cur * HID + lane * 4];
      atomicAdd(o + 0, acc.x); atomicAdd(o + 1, acc.y);
      atomicAdd(o + 2, acc.z); atomicAdd(o + 3, acc.w);
      acc = (float4){0.f, 0.f, 0.f, 0.f};
      cur = b;
    }
    acc.x += w * xv.x; acc.y += w * xv.y;
    acc.z += w * xv.z; acc.w += w * xv.w;
    xv = xnext;
  }
  {
    float* o = &out[(long)cur * HID + lane * 4];
    atomicAdd(o + 0, acc.x); atomicAdd(o + 1, acc.y);
    atomicAdd(o + 2, acc.z); atomicAdd(o + 3, acc.w);
  }
}

extern "C" void kernel_launch(void* const* d_in, const int* in_sizes, int n_in,
                              void* d_out, int out_size, void* d_ws, size_t ws_size,
                              hipStream_t stream){
  const float* x     = (const float*)d_in[0];
  const int*   batch = (const int*)d_in[1];
  const float* w1    = (const float*)d_in[2];
  const float* b1    = (const float*)d_in[3];
  const float* w2    = (const float*)d_in[4];
  const float* b2    = (const float*)d_in[5];
  float* out = (float*)d_out;

  char* ws = (char*)d_ws;
  unsigned short* w1f = (unsigned short*)ws;            // 65536 B
  float* escore = (float*)(ws + 65536);                 // 4,000,000 B
  float* denom  = (float*)(ws + 65536 + 4000000);       // 4096 B

  hipMemsetAsync(denom, 0, 4096, stream);
  hipMemsetAsync(d_out, 0, (size_t)out_size * sizeof(float), stream);

  k_prep<<<16, 256, 0, stream>>>(w1, w1f);
  k_score<<<2048, 256, 0, stream>>>(x, w1f, b1, w2, b2, batch, escore, denom, N_NODES / 64);
  k_pool<<<(N_NODES + 1023) / 1024, 256, 0, stream>>>(x, batch, escore, denom, out);
}